// Round 6
// baseline (109.661 us; speedup 1.0000x reference)
//
#include <hip/hip_runtime.h>

#define N_IN   128
#define LAYERS 6
#define N_H    320
#define DEG    32
#define N_OUT  18
#define N_TOTAL (N_IN + LAYERS * N_H)       // 2048
#define BB     8                            // batch elements per block
#define N_HID_UNITS (LAYERS * N_H)          // 1920
#define N_UNITS (N_HID_UNITS + N_OUT)       // 1938

typedef _Float16 half2_t __attribute__((ext_vector_type(2)));
typedef _Float16 half8_t __attribute__((ext_vector_type(8)));

__device__ __forceinline__ float fast_tanh(float x) {
    float e = __expf(2.0f * x);
    return 1.0f - 2.0f * __builtin_amdgcn_rcpf(e + 1.0f);
}

// fused table per unit (32 dwords): [0..15] = offset pairs (idx0*16 | idx1*16<<16),
//                                   [16..31] = weight half2 pairs (w_{2q}, w_{2q+1})
__global__ __launch_bounds__(64) void pack_kernel(
    const int* __restrict__ hid_src, const float* __restrict__ hid_w,
    const int* __restrict__ out_src, const float* __restrict__ out_w,
    unsigned int* __restrict__ fused)
{
    int u = blockIdx.x * 64 + threadIdx.x;
    if (u >= N_UNITS) return;
    const int*   src;
    const float* w;
    if (u < N_HID_UNITS) { src = hid_src + u * DEG;                 w = hid_w + u * DEG; }
    else                 { src = out_src + (u - N_HID_UNITS) * DEG; w = out_w + (u - N_HID_UNITS) * DEG; }
    unsigned int* dst = fused + u * 32;
    for (int q = 0; q < 16; ++q) {
        unsigned o0 = (unsigned)src[2 * q]     << 4;   // byte offset into 16B rows
        unsigned o1 = (unsigned)src[2 * q + 1] << 4;
        dst[q] = o0 | (o1 << 16);
        half2_t wp;
        wp[0] = (_Float16)w[2 * q];
        wp[1] = (_Float16)w[2 * q + 1];
        dst[16 + q] = __builtin_bit_cast(unsigned int, wp);
    }
}

__device__ __forceinline__ half2_t h2(unsigned d) { return __builtin_bit_cast(half2_t, d); }

// One tap-pair: gather two 16B rows (8 f16 batch elems each); accumulate with
// v_pk_fma_f16 against splatted weights. acc0..acc3 are half2 (batch pairs
// (0,1),(2,3),(4,5),(6,7)). All named scalars — nothing can fall to scratch.
#define DOT_STEP(OD, WD) do {                                              \
    unsigned _off0 = (OD) & 0xffffu;                                       \
    unsigned _off1 = (OD) >> 16;                                           \
    uint4 _g0 = *(const uint4*)(sA + _off0);                               \
    uint4 _g1 = *(const uint4*)(sA + _off1);                               \
    half2_t _wa = h2(__builtin_amdgcn_perm((WD), (WD), 0x01000100u));      \
    half2_t _wb = h2(__builtin_amdgcn_perm((WD), (WD), 0x03020302u));      \
    acc0 = h2(_g0.x) * _wa + acc0;                                         \
    acc1 = h2(_g0.y) * _wa + acc1;                                         \
    acc2 = h2(_g0.z) * _wa + acc2;                                         \
    acc3 = h2(_g0.w) * _wa + acc3;                                         \
    acc0 = h2(_g1.x) * _wb + acc0;                                         \
    acc1 = h2(_g1.y) * _wb + acc1;                                         \
    acc2 = h2(_g1.z) * _wb + acc2;                                         \
    acc3 = h2(_g1.w) * _wb + acc3;                                         \
} while (0)

// Load the unit's fused table (8 x uint4, L2-hot) and run 16 tap-pairs.
#define GATHER_UNIT(BASE) do {                                             \
    const uint4* _t = ftab + (BASE);                                       \
    uint4 _fo0 = _t[0], _fo1 = _t[1], _fo2 = _t[2], _fo3 = _t[3];          \
    uint4 _fw0 = _t[4], _fw1 = _t[5], _fw2 = _t[6], _fw3 = _t[7];          \
    DOT_STEP(_fo0.x, _fw0.x); DOT_STEP(_fo0.y, _fw0.y);                    \
    DOT_STEP(_fo0.z, _fw0.z); DOT_STEP(_fo0.w, _fw0.w);                    \
    DOT_STEP(_fo1.x, _fw1.x); DOT_STEP(_fo1.y, _fw1.y);                    \
    DOT_STEP(_fo1.z, _fw1.z); DOT_STEP(_fo1.w, _fw1.w);                    \
    DOT_STEP(_fo2.x, _fw2.x); DOT_STEP(_fo2.y, _fw2.y);                    \
    DOT_STEP(_fo2.z, _fw2.z); DOT_STEP(_fo2.w, _fw2.w);                    \
    DOT_STEP(_fo3.x, _fw3.x); DOT_STEP(_fo3.y, _fw3.y);                    \
    DOT_STEP(_fo3.z, _fw3.z); DOT_STEP(_fo3.w, _fw3.w);                    \
} while (0)

__global__ __launch_bounds__(N_H, 5) void policy_kernel(
    const float* __restrict__ obs,       // [B][N_IN]
    const uint4* __restrict__ ftab,      // [N_UNITS][8] fused offsets+weights
    const float* __restrict__ hid_b,     // [L][N_H]
    const float* __restrict__ out_b,     // [N_OUT]
    float*       __restrict__ out)       // [B][N_OUT]
{
    // acts row r = 8 x f16 (one per batch elem) = 16 B -> one ds_read_b128/gather
    __shared__ alignas(16) unsigned char sA[N_TOTAL * 16];   // 32 KB

    const int tid = threadIdx.x;
    const int b0  = blockIdx.x * BB;
    const int n   = tid;

    if (tid < N_IN) {
        half8_t hv;
        #pragma unroll
        for (int j = 0; j < BB; ++j) hv[j] = (_Float16)obs[(b0 + j) * N_IN + tid];
        *(half8_t*)(sA + tid * 16) = hv;
    }
    __syncthreads();

    for (int l = 0; l < LAYERS; ++l) {
        half2_t acc0 = {0, 0}, acc1 = {0, 0}, acc2 = {0, 0}, acc3 = {0, 0};
        GATHER_UNIT((l * N_H + n) * 8);

        float bias = hid_b[l * N_H + n];
        half8_t hv;
        hv[0] = (_Float16)fast_tanh((float)acc0[0] + bias);
        hv[1] = (_Float16)fast_tanh((float)acc0[1] + bias);
        hv[2] = (_Float16)fast_tanh((float)acc1[0] + bias);
        hv[3] = (_Float16)fast_tanh((float)acc1[1] + bias);
        hv[4] = (_Float16)fast_tanh((float)acc2[0] + bias);
        hv[5] = (_Float16)fast_tanh((float)acc2[1] + bias);
        hv[6] = (_Float16)fast_tanh((float)acc3[0] + bias);
        hv[7] = (_Float16)fast_tanh((float)acc3[1] + bias);
        // this layer writes rows it never reads; one barrier per layer suffices
        *(half8_t*)(sA + (N_IN + l * N_H + n) * 16) = hv;
        __syncthreads();
    }

    if (n < N_OUT) {
        half2_t acc0 = {0, 0}, acc1 = {0, 0}, acc2 = {0, 0}, acc3 = {0, 0};
        GATHER_UNIT((N_HID_UNITS + n) * 8);
        float bias = out_b[n];
        out[(b0 + 0) * N_OUT + n] = fast_tanh((float)acc0[0] + bias);
        out[(b0 + 1) * N_OUT + n] = fast_tanh((float)acc0[1] + bias);
        out[(b0 + 2) * N_OUT + n] = fast_tanh((float)acc1[0] + bias);
        out[(b0 + 3) * N_OUT + n] = fast_tanh((float)acc1[1] + bias);
        out[(b0 + 4) * N_OUT + n] = fast_tanh((float)acc2[0] + bias);
        out[(b0 + 5) * N_OUT + n] = fast_tanh((float)acc2[1] + bias);
        out[(b0 + 6) * N_OUT + n] = fast_tanh((float)acc3[0] + bias);
        out[(b0 + 7) * N_OUT + n] = fast_tanh((float)acc3[1] + bias);
    }
}

extern "C" void kernel_launch(void* const* d_in, const int* in_sizes, int n_in,
                              void* d_out, int out_size, void* d_ws, size_t ws_size,
                              hipStream_t stream) {
    const float* obs     = (const float*)d_in[0];
    const int*   hid_src = (const int*)  d_in[1];
    const float* hid_w   = (const float*)d_in[2];
    const float* hid_b   = (const float*)d_in[3];
    const int*   out_src = (const int*)  d_in[4];
    const float* out_w   = (const float*)d_in[5];
    const float* out_b   = (const float*)d_in[6];
    float* out = (float*)d_out;
    unsigned int* fused = (unsigned int*)d_ws;   // 1938*32*4 = 248 KB

    const int batch = in_sizes[0] / N_IN;   // 8192

    pack_kernel<<<(N_UNITS + 63) / 64, 64, 0, stream>>>(
        hid_src, hid_w, out_src, out_w, fused);
    policy_kernel<<<batch / BB, N_H, 0, stream>>>(
        obs, (const uint4*)fused, hid_b, out_b, out);
}